// Round 1
// baseline (12445.508 us; speedup 1.0000x reference)
//
#include <hip/hip_runtime.h>

// GRU classifier: x[256,512,128] -> GRU(H=512) -> head -> out[256,1000]
// Strategy: persistent scan kernel, weights resident in VGPRs as bf16 MFMA
// fragments, fp32 state carry, XCD-local 16-block group barriers per step.

#define NB 256   // batch
#define NH 512   // hidden
#define NI 128   // input dim
#define NC 1000  // classes
#define NS 512   // seq len

typedef __attribute__((ext_vector_type(8))) short bf16x8;
typedef __attribute__((ext_vector_type(4))) float f32x4;

__device__ __forceinline__ unsigned short f2bf(float f) {
    unsigned u = __builtin_bit_cast(unsigned, f);
    return (unsigned short)((u + 0x7FFFu + ((u >> 16) & 1u)) >> 16);  // RNE
}

__device__ __forceinline__ bf16x8 pack8(const float* v) {
    bf16x8 r;
#pragma unroll
    for (int i = 0; i < 8; ++i) r[i] = (short)f2bf(v[i]);
    return r;
}

__global__ void gru_init_ws(uint4* __restrict__ hb, uint4* __restrict__ cn) {
    const int i = blockIdx.x * 256 + threadIdx.x;
    const uint4 z = make_uint4(0u, 0u, 0u, 0u);
    if (i < 16384) hb[i] = z;                       // hbuf[0]: 256*512 bf16 = 256KB
    else if (i < 16384 + 2048) cn[i - 16384] = z;   // counters: 32KB
}

// 256 blocks x 256 threads. block(bid): group g=bid&15 (rows 16g..16g+16),
// jb=bid>>4 (hidden cols 32jb..32jb+32). 4 waves: ch=w&1 (16-col half),
// kh=w>>1 (K half). Each wave: 3 gate N-tiles x 16x16x32 MFMA.
__global__ void __launch_bounds__(256, 1) gru_scan(
    const float* __restrict__ x,
    const float* __restrict__ Wih,
    const float* __restrict__ Whh,
    const float* __restrict__ bih,
    const float* __restrict__ bhh,
    unsigned short* __restrict__ hbuf,   // [2][NB][NH] bf16 (double buffer)
    float* __restrict__ hT,              // [NB][NH] fp32 final state
    unsigned int* __restrict__ cnt)      // [16][NS] phased barrier counters
{
    const int tid = threadIdx.x;
    const int l   = tid & 63;
    const int w   = tid >> 6;
    const int ch  = w & 1;
    const int kh  = w >> 1;
    const int bid = blockIdx.x;
    const int g   = bid & 15;
    const int jb  = bid >> 4;
    const int r0  = g << 4;
    const int cw0 = (jb << 5) + (ch << 4);
    const int l15 = l & 15;
    const int lq  = l >> 4;

    __shared__ float part[4][6][64][4];  // cross-wave K-reduction exchange

    // ---- preload weight fragments into registers (fp32 -> bf16 RNE) ----
    // B-frag layout (16x16x32): lane holds W[col = l&15][k = (l>>4)*8 + 0..7]
    bf16x8 whh[3][8];
#pragma unroll
    for (int nt = 0; nt < 3; ++nt) {
        const int jr = nt * NH + cw0 + l15;
        const float* wr = Whh + jr * NH;
#pragma unroll
        for (int ks = 0; ks < 8; ++ks) {
            const int k0 = kh * 256 + ks * 32 + lq * 8;
            float tmp[8];
            *(f32x4*)(tmp)     = *(const f32x4*)(wr + k0);
            *(f32x4*)(tmp + 4) = *(const f32x4*)(wr + k0 + 4);
            whh[nt][ks] = pack8(tmp);
        }
    }
    bf16x8 wih[3][2];
#pragma unroll
    for (int nt = 0; nt < 3; ++nt) {
        const int jr = nt * NH + cw0 + l15;
        const float* wr = Wih + jr * NI;
#pragma unroll
        for (int ks = 0; ks < 2; ++ks) {
            const int k0 = kh * 64 + ks * 32 + lq * 8;
            float tmp[8];
            *(f32x4*)(tmp)     = *(const f32x4*)(wr + k0);
            *(f32x4*)(tmp + 4) = *(const f32x4*)(wr + k0 + 4);
            wih[nt][ks] = pack8(tmp);
        }
    }

    const int c_col = cw0 + l15;
    float bi0 = bih[c_col], bi1 = bih[NH + c_col], bi2 = bih[2 * NH + c_col];
    float bh0 = bhh[c_col], bh1 = bhh[NH + c_col], bh2 = bhh[2 * NH + c_col];
    if (kh != 0) { bi0 = bi1 = bi2 = bh0 = bh1 = bh2 = 0.f; }  // bias counted once

    float hold0 = 0.f, hold1 = 0.f;  // fp32 state carry for this wave's 2 cells

    const int arow = r0 + l15;
    const int aoff = arow * NH + kh * 256 + lq * 8;         // A-frag base (elems)
    const float* xptr0 = x + arow * (NS * NI) + kh * 64 + lq * 8;

    // x fragments for t=0
    f32x4 xp0 = *(const f32x4*)(xptr0 + 0);
    f32x4 xp1 = *(const f32x4*)(xptr0 + 4);
    f32x4 xp2 = *(const f32x4*)(xptr0 + 32);
    f32x4 xp3 = *(const f32x4*)(xptr0 + 36);

    unsigned int* cg = cnt + (g << 9);

    for (int t = 0; t < NS; ++t) {
        const int cur = t & 1;
        const unsigned short* hr_ = hbuf + cur * (NB * NH);
        unsigned short* hw_ = hbuf + (cur ^ 1) * (NB * NH);

        // issue A-frag loads (h, bf16, from this group's rows; XCD-local L2)
        bf16x8 afr[8];
#pragma unroll
        for (int ks = 0; ks < 8; ++ks)
            afr[ks] = *(const bf16x8*)(hr_ + aoff + ks * 32);

        f32x4 hg0 = {bh0, bh0, bh0, bh0}, hg1 = {bh1, bh1, bh1, bh1}, hg2 = {bh2, bh2, bh2, bh2};
        f32x4 xg0 = {bi0, bi0, bi0, bi0}, xg1 = {bi1, bi1, bi1, bi1}, xg2 = {bi2, bi2, bi2, bi2};

        // x-projection MFMAs (data already in regs; overlaps A-load latency)
        {
            float xt[16];
            *(f32x4*)(xt)      = xp0; *(f32x4*)(xt + 4)  = xp1;
            *(f32x4*)(xt + 8)  = xp2; *(f32x4*)(xt + 12) = xp3;
            bf16x8 xf0 = pack8(xt), xf1 = pack8(xt + 8);
            xg0 = __builtin_amdgcn_mfma_f32_16x16x32_bf16(xf0, wih[0][0], xg0, 0, 0, 0);
            xg1 = __builtin_amdgcn_mfma_f32_16x16x32_bf16(xf0, wih[1][0], xg1, 0, 0, 0);
            xg2 = __builtin_amdgcn_mfma_f32_16x16x32_bf16(xf0, wih[2][0], xg2, 0, 0, 0);
            xg0 = __builtin_amdgcn_mfma_f32_16x16x32_bf16(xf1, wih[0][1], xg0, 0, 0, 0);
            xg1 = __builtin_amdgcn_mfma_f32_16x16x32_bf16(xf1, wih[1][1], xg1, 0, 0, 0);
            xg2 = __builtin_amdgcn_mfma_f32_16x16x32_bf16(xf1, wih[2][1], xg2, 0, 0, 0);
        }

        // hidden-projection MFMAs (24 per wave, K-half)
#pragma unroll
        for (int ks = 0; ks < 8; ++ks) {
            hg0 = __builtin_amdgcn_mfma_f32_16x16x32_bf16(afr[ks], whh[0][ks], hg0, 0, 0, 0);
            hg1 = __builtin_amdgcn_mfma_f32_16x16x32_bf16(afr[ks], whh[1][ks], hg1, 0, 0, 0);
            hg2 = __builtin_amdgcn_mfma_f32_16x16x32_bf16(afr[ks], whh[2][ks], hg2, 0, 0, 0);
        }

        // prefetch x fragments for t+1 (latency hides under barrier spin)
        if (t + 1 < NS) {
            const float* xp = xptr0 + (t + 1) * NI;
            xp0 = *(const f32x4*)(xp + 0);
            xp1 = *(const f32x4*)(xp + 4);
            xp2 = *(const f32x4*)(xp + 32);
            xp3 = *(const f32x4*)(xp + 36);
        }

        // ---- cross-wave (K-half) reduction via LDS ----
        *(f32x4*)&part[w][0][l][0] = hg0;
        *(f32x4*)&part[w][1][l][0] = hg1;
        *(f32x4*)&part[w][2][l][0] = hg2;
        *(f32x4*)&part[w][3][l][0] = xg0;
        *(f32x4*)&part[w][4][l][0] = xg1;
        *(f32x4*)&part[w][5][l][0] = xg2;
        __syncthreads();
        const int pw = w ^ 2;  // partner: same ch, other kh
        const f32x4 ph0 = *(const f32x4*)&part[pw][0][l][0];
        const f32x4 ph1 = *(const f32x4*)&part[pw][1][l][0];
        const f32x4 ph2 = *(const f32x4*)&part[pw][2][l][0];
        const f32x4 px0 = *(const f32x4*)&part[pw][3][l][0];
        const f32x4 px1 = *(const f32x4*)&part[pw][4][l][0];
        const f32x4 px2 = *(const f32x4*)&part[pw][5][l][0];

        float vh0[2], vh1[2], vh2[2], vx0[2], vx1[2], vx2[2];
        if (kh == 0) {  // wave handles accumulator elems i = {0,1}
            vh0[0] = hg0[0] + ph0[0]; vh0[1] = hg0[1] + ph0[1];
            vh1[0] = hg1[0] + ph1[0]; vh1[1] = hg1[1] + ph1[1];
            vh2[0] = hg2[0] + ph2[0]; vh2[1] = hg2[1] + ph2[1];
            vx0[0] = xg0[0] + px0[0]; vx0[1] = xg0[1] + px0[1];
            vx1[0] = xg1[0] + px1[0]; vx1[1] = xg1[1] + px1[1];
            vx2[0] = xg2[0] + px2[0]; vx2[1] = xg2[1] + px2[1];
        } else {        // elems i = {2,3}
            vh0[0] = hg0[2] + ph0[2]; vh0[1] = hg0[3] + ph0[3];
            vh1[0] = hg1[2] + ph1[2]; vh1[1] = hg1[3] + ph1[3];
            vh2[0] = hg2[2] + ph2[2]; vh2[1] = hg2[3] + ph2[3];
            vx0[0] = xg0[2] + px0[2]; vx0[1] = xg0[3] + px0[3];
            vx1[0] = xg1[2] + px1[2]; vx1[1] = xg1[3] + px1[3];
            vx2[0] = xg2[2] + px2[2]; vx2[1] = xg2[3] + px2[3];
        }

        // ---- gates + state update (fp32 carry in registers) ----
#pragma unroll
        for (int q = 0; q < 2; ++q) {
            const float rr = __builtin_amdgcn_rcpf(1.f + __expf(-(vx0[q] + vh0[q])));
            const float zz = __builtin_amdgcn_rcpf(1.f + __expf(-(vx1[q] + vh1[q])));
            const float a  = vx2[q] + rr * vh2[q];
            const float e2 = __expf(2.f * a);
            const float nn = (e2 - 1.f) * __builtin_amdgcn_rcpf(e2 + 1.f);
            const float hp = q ? hold1 : hold0;
            const float hnew = (1.f - zz) * nn + zz * hp;
            if (q) hold1 = hnew; else hold0 = hnew;
            const int row = r0 + lq * 4 + (kh * 2 + q);
            hw_[row * NH + c_col] = f2bf(hnew);
            if (t == NS - 1) hT[row * NH + c_col] = hnew;
        }

        // ---- XCD-local 16-block phased barrier (skip after last step) ----
        if (t < NS - 1) {
            __threadfence();
            __syncthreads();
            if (tid == 0) {
                __hip_atomic_fetch_add(cg + t, 1u, __ATOMIC_RELEASE, __HIP_MEMORY_SCOPE_AGENT);
                while (__hip_atomic_load(cg + t, __ATOMIC_ACQUIRE, __HIP_MEMORY_SCOPE_AGENT) < 16u)
                    __builtin_amdgcn_s_sleep(1);
            }
            __syncthreads();
        }
    }
}

// out[256,1000] = hT[256,512] @ W_head^T + b_head, pure fp32.
__global__ void __launch_bounds__(256, 1) gru_head(
    const float* __restrict__ hT,
    const float* __restrict__ Wh,
    const float* __restrict__ bh,
    float* __restrict__ out)
{
    __shared__ float hs[16 * 512];
    const int tid = threadIdx.x;
    const int rg  = blockIdx.x;   // 16 row groups of 16
    const int cgp = blockIdx.y;   // 16 col groups of 64
    const float* src = hT + rg * (16 * 512);
#pragma unroll
    for (int i = 0; i < 32; ++i) hs[tid + 256 * i] = src[tid + 256 * i];
    __syncthreads();
    const int col = (cgp << 6) + (tid & 63);
    const int rb  = (tid >> 6) << 2;
    if (col < NC) {
        const float* wr = Wh + col * NH;
        float a0 = 0.f, a1 = 0.f, a2 = 0.f, a3 = 0.f;
        for (int k = 0; k < NH; k += 4) {
            const f32x4 wv = *(const f32x4*)(wr + k);
            const f32x4 h0 = *(const f32x4*)&hs[(rb + 0) * NH + k];
            const f32x4 h1 = *(const f32x4*)&hs[(rb + 1) * NH + k];
            const f32x4 h2 = *(const f32x4*)&hs[(rb + 2) * NH + k];
            const f32x4 h3 = *(const f32x4*)&hs[(rb + 3) * NH + k];
#pragma unroll
            for (int j = 0; j < 4; ++j) {
                a0 = fmaf(wv[j], h0[j], a0);
                a1 = fmaf(wv[j], h1[j], a1);
                a2 = fmaf(wv[j], h2[j], a2);
                a3 = fmaf(wv[j], h3[j], a3);
            }
        }
        const float bb = bh[col];
        const int orow = (rg << 4) + rb;
        out[(orow + 0) * NC + col] = a0 + bb;
        out[(orow + 1) * NC + col] = a1 + bb;
        out[(orow + 2) * NC + col] = a2 + bb;
        out[(orow + 3) * NC + col] = a3 + bb;
    }
}

extern "C" void kernel_launch(void* const* d_in, const int* in_sizes, int n_in,
                              void* d_out, int out_size, void* d_ws, size_t ws_size,
                              hipStream_t stream)
{
    (void)in_sizes; (void)n_in; (void)out_size; (void)ws_size;
    const float* x     = (const float*)d_in[0];
    const float* Wih   = (const float*)d_in[1];
    const float* Whh   = (const float*)d_in[2];
    const float* bih   = (const float*)d_in[3];
    const float* bhh   = (const float*)d_in[4];
    const float* Whead = (const float*)d_in[5];
    const float* bhead = (const float*)d_in[6];
    float* out = (float*)d_out;

    char* ws = (char*)d_ws;
    unsigned short* hbuf = (unsigned short*)ws;                        // 2*256*512 bf16 = 512KB
    unsigned int*   cnt  = (unsigned int*)(ws + 2 * NB * NH * 2);      // 16*512 u32  = 32KB
    float*          hT   = (float*)(ws + 2 * NB * NH * 2 + 16 * NS * 4); // 256*512 f32 = 512KB

    gru_init_ws<<<72, 256, 0, stream>>>((uint4*)hbuf, (uint4*)cnt);
    gru_scan<<<256, 256, 0, stream>>>(x, Wih, Whh, bih, bhh, hbuf, hT, cnt);
    gru_head<<<dim3(16, 16), 256, 0, stream>>>(hT, Whead, bhead, out);
}

// Round 3
// 1731.529 us; speedup vs baseline: 7.1876x; 7.1876x over previous
//
#include <hip/hip_runtime.h>

// GRU classifier: x[256,512,128] -> GRU(H=512) -> head -> out[256,1000]
// Persistent scan kernel, weights resident in VGPRs as bf16 MFMA fragments,
// fp32 state carry. Cross-block h exchange + barriers via RELAXED agent-scope
// atomics (performed at Infinity Cache) -- NO fences, NO L2 writeback/inv.

#define NB 256   // batch
#define NH 512   // hidden
#define NI 128   // input dim
#define NC 1000  // classes
#define NS 512   // seq len

typedef __attribute__((ext_vector_type(8))) short bf16x8;
typedef __attribute__((ext_vector_type(4))) float f32x4;

__device__ __forceinline__ unsigned short f2bf(float f) {
    unsigned u = __builtin_bit_cast(unsigned, f);
    return (unsigned short)((u + 0x7FFFu + ((u >> 16) & 1u)) >> 16);  // RNE
}

__device__ __forceinline__ bf16x8 pack8(const float* v) {
    bf16x8 r;
#pragma unroll
    for (int i = 0; i < 8; ++i) r[i] = (short)f2bf(v[i]);
    return r;
}

__device__ __forceinline__ unsigned long long ld_agent_u64(const unsigned long long* p) {
    return __hip_atomic_load(p, __ATOMIC_RELAXED, __HIP_MEMORY_SCOPE_AGENT);
}
__device__ __forceinline__ void st_agent_u16(unsigned short* p, unsigned short v) {
    __hip_atomic_store(p, v, __ATOMIC_RELAXED, __HIP_MEMORY_SCOPE_AGENT);
}

// zero hbuf[0] (256KB) + counters (32KB) with agent-scope stores so the
// IC-level view is zeroed regardless of which XCD ran the init block.
__global__ void gru_init_ws(unsigned long long* __restrict__ hb,
                            unsigned long long* __restrict__ cn) {
    const int i = blockIdx.x * 256 + threadIdx.x;
    if (i < 32768)
        __hip_atomic_store(hb + i, 0ull, __ATOMIC_RELAXED, __HIP_MEMORY_SCOPE_AGENT);
    else if (i < 32768 + 4096)
        __hip_atomic_store(cn + (i - 32768), 0ull, __ATOMIC_RELAXED, __HIP_MEMORY_SCOPE_AGENT);
}

// 256 blocks x 256 threads. block(bid): group g=bid&15 (rows 16g..16g+16),
// jb=bid>>4 (hidden cols 32jb..32jb+32). 4 waves: ch=w&1 (16-col half),
// kh=w>>1 (K half). Each wave: 3 gate N-tiles x 16x16x32 MFMA.
__global__ void __launch_bounds__(256, 1) gru_scan(
    const float* __restrict__ x,
    const float* __restrict__ Wih,
    const float* __restrict__ Whh,
    const float* __restrict__ bih,
    const float* __restrict__ bhh,
    unsigned short* __restrict__ hbuf,   // [2][NB][NH] bf16 (double buffer, IC-coherent)
    float* __restrict__ hT,              // [NB][NH] fp32 final state
    unsigned int* __restrict__ cnt)      // [16][NS] phased barrier counters
{
    const int tid = threadIdx.x;
    const int l   = tid & 63;
    const int w   = tid >> 6;
    const int ch  = w & 1;
    const int kh  = w >> 1;
    const int bid = blockIdx.x;
    const int g   = bid & 15;
    const int jb  = bid >> 4;
    const int r0  = g << 4;
    const int cw0 = (jb << 5) + (ch << 4);
    const int l15 = l & 15;
    const int lq  = l >> 4;

    __shared__ float part[4][6][64][4];  // cross-wave K-reduction exchange

    // ---- preload weight fragments into registers (fp32 -> bf16 RNE) ----
    // B-frag layout (16x16x32): lane holds W[col = l&15][k = (l>>4)*8 + 0..7]
    bf16x8 whh[3][8];
#pragma unroll
    for (int nt = 0; nt < 3; ++nt) {
        const int jr = nt * NH + cw0 + l15;
        const float* wr = Whh + jr * NH;
#pragma unroll
        for (int ks = 0; ks < 8; ++ks) {
            const int k0 = kh * 256 + ks * 32 + lq * 8;
            float tmp[8];
            *(f32x4*)(tmp)     = *(const f32x4*)(wr + k0);
            *(f32x4*)(tmp + 4) = *(const f32x4*)(wr + k0 + 4);
            whh[nt][ks] = pack8(tmp);
        }
    }
    bf16x8 wih[3][2];
#pragma unroll
    for (int nt = 0; nt < 3; ++nt) {
        const int jr = nt * NH + cw0 + l15;
        const float* wr = Wih + jr * NI;
#pragma unroll
        for (int ks = 0; ks < 2; ++ks) {
            const int k0 = kh * 64 + ks * 32 + lq * 8;
            float tmp[8];
            *(f32x4*)(tmp)     = *(const f32x4*)(wr + k0);
            *(f32x4*)(tmp + 4) = *(const f32x4*)(wr + k0 + 4);
            wih[nt][ks] = pack8(tmp);
        }
    }

    const int c_col = cw0 + l15;
    float bi0 = bih[c_col], bi1 = bih[NH + c_col], bi2 = bih[2 * NH + c_col];
    float bh0 = bhh[c_col], bh1 = bhh[NH + c_col], bh2 = bhh[2 * NH + c_col];
    if (kh != 0) { bi0 = bi1 = bi2 = bh0 = bh1 = bh2 = 0.f; }  // bias counted once

    float hold0 = 0.f, hold1 = 0.f;  // fp32 state carry for this wave's 2 cells

    const int arow = r0 + l15;
    const int aoff = arow * NH + kh * 256 + lq * 8;         // A-frag base (elems)
    const float* xptr0 = x + arow * (NS * NI) + kh * 64 + lq * 8;

    // x fragments for t=0
    f32x4 xp0 = *(const f32x4*)(xptr0 + 0);
    f32x4 xp1 = *(const f32x4*)(xptr0 + 4);
    f32x4 xp2 = *(const f32x4*)(xptr0 + 32);
    f32x4 xp3 = *(const f32x4*)(xptr0 + 36);

    unsigned int* cg = cnt + (g << 9);

    for (int t = 0; t < NS; ++t) {
        const int cur = t & 1;
        const unsigned short* hr_ = hbuf + cur * (NB * NH);
        unsigned short* hw_ = hbuf + (cur ^ 1) * (NB * NH);

        // issue A-frag loads (h, bf16, relaxed agent-scope -> served by IC)
        const unsigned long long* hq = (const unsigned long long*)(hr_ + aoff);
        bf16x8 afr[8];
#pragma unroll
        for (int ks = 0; ks < 8; ++ks) {
            union { unsigned long long q[2]; bf16x8 v; } u;
            u.q[0] = ld_agent_u64(hq + ks * 8 + 0);
            u.q[1] = ld_agent_u64(hq + ks * 8 + 1);
            afr[ks] = u.v;
        }

        f32x4 hg0 = {bh0, bh0, bh0, bh0}, hg1 = {bh1, bh1, bh1, bh1}, hg2 = {bh2, bh2, bh2, bh2};
        f32x4 xg0 = {bi0, bi0, bi0, bi0}, xg1 = {bi1, bi1, bi1, bi1}, xg2 = {bi2, bi2, bi2, bi2};

        // x-projection MFMAs (data already in regs; overlaps A-load latency)
        {
            float xt[16];
            *(f32x4*)(xt)      = xp0; *(f32x4*)(xt + 4)  = xp1;
            *(f32x4*)(xt + 8)  = xp2; *(f32x4*)(xt + 12) = xp3;
            bf16x8 xf0 = pack8(xt), xf1 = pack8(xt + 8);
            xg0 = __builtin_amdgcn_mfma_f32_16x16x32_bf16(xf0, wih[0][0], xg0, 0, 0, 0);
            xg1 = __builtin_amdgcn_mfma_f32_16x16x32_bf16(xf0, wih[1][0], xg1, 0, 0, 0);
            xg2 = __builtin_amdgcn_mfma_f32_16x16x32_bf16(xf0, wih[2][0], xg2, 0, 0, 0);
            xg0 = __builtin_amdgcn_mfma_f32_16x16x32_bf16(xf1, wih[0][1], xg0, 0, 0, 0);
            xg1 = __builtin_amdgcn_mfma_f32_16x16x32_bf16(xf1, wih[1][1], xg1, 0, 0, 0);
            xg2 = __builtin_amdgcn_mfma_f32_16x16x32_bf16(xf1, wih[2][1], xg2, 0, 0, 0);
        }

        // hidden-projection MFMAs (24 per wave, K-half)
#pragma unroll
        for (int ks = 0; ks < 8; ++ks) {
            hg0 = __builtin_amdgcn_mfma_f32_16x16x32_bf16(afr[ks], whh[0][ks], hg0, 0, 0, 0);
            hg1 = __builtin_amdgcn_mfma_f32_16x16x32_bf16(afr[ks], whh[1][ks], hg1, 0, 0, 0);
            hg2 = __builtin_amdgcn_mfma_f32_16x16x32_bf16(afr[ks], whh[2][ks], hg2, 0, 0, 0);
        }

        // prefetch x fragments for t+1 (plain loads, L1/L2-cached)
        if (t + 1 < NS) {
            const float* xp = xptr0 + (t + 1) * NI;
            xp0 = *(const f32x4*)(xp + 0);
            xp1 = *(const f32x4*)(xp + 4);
            xp2 = *(const f32x4*)(xp + 32);
            xp3 = *(const f32x4*)(xp + 36);
        }

        // ---- cross-wave (K-half) reduction via LDS ----
        *(f32x4*)&part[w][0][l][0] = hg0;
        *(f32x4*)&part[w][1][l][0] = hg1;
        *(f32x4*)&part[w][2][l][0] = hg2;
        *(f32x4*)&part[w][3][l][0] = xg0;
        *(f32x4*)&part[w][4][l][0] = xg1;
        *(f32x4*)&part[w][5][l][0] = xg2;
        __syncthreads();
        const int pw = w ^ 2;  // partner: same ch, other kh
        const f32x4 ph0 = *(const f32x4*)&part[pw][0][l][0];
        const f32x4 ph1 = *(const f32x4*)&part[pw][1][l][0];
        const f32x4 ph2 = *(const f32x4*)&part[pw][2][l][0];
        const f32x4 px0 = *(const f32x4*)&part[pw][3][l][0];
        const f32x4 px1 = *(const f32x4*)&part[pw][4][l][0];
        const f32x4 px2 = *(const f32x4*)&part[pw][5][l][0];

        float vh0[2], vh1[2], vh2[2], vx0[2], vx1[2], vx2[2];
        if (kh == 0) {  // wave handles accumulator elems i = {0,1}
            vh0[0] = hg0[0] + ph0[0]; vh0[1] = hg0[1] + ph0[1];
            vh1[0] = hg1[0] + ph1[0]; vh1[1] = hg1[1] + ph1[1];
            vh2[0] = hg2[0] + ph2[0]; vh2[1] = hg2[1] + ph2[1];
            vx0[0] = xg0[0] + px0[0]; vx0[1] = xg0[1] + px0[1];
            vx1[0] = xg1[0] + px1[0]; vx1[1] = xg1[1] + px1[1];
            vx2[0] = xg2[0] + px2[0]; vx2[1] = xg2[1] + px2[1];
        } else {        // elems i = {2,3}
            vh0[0] = hg0[2] + ph0[2]; vh0[1] = hg0[3] + ph0[3];
            vh1[0] = hg1[2] + ph1[2]; vh1[1] = hg1[3] + ph1[3];
            vh2[0] = hg2[2] + ph2[2]; vh2[1] = hg2[3] + ph2[3];
            vx0[0] = xg0[2] + px0[2]; vx0[1] = xg0[3] + px0[3];
            vx1[0] = xg1[2] + px1[2]; vx1[1] = xg1[3] + px1[3];
            vx2[0] = xg2[2] + px2[2]; vx2[1] = xg2[3] + px2[3];
        }

        // ---- gates + state update (fp32 carry in registers) ----
#pragma unroll
        for (int q = 0; q < 2; ++q) {
            const float rr = __builtin_amdgcn_rcpf(1.f + __expf(-(vx0[q] + vh0[q])));
            const float zz = __builtin_amdgcn_rcpf(1.f + __expf(-(vx1[q] + vh1[q])));
            const float a  = vx2[q] + rr * vh2[q];
            const float e2 = __expf(2.f * a);
            const float nn = (e2 - 1.f) * __builtin_amdgcn_rcpf(e2 + 1.f);
            const float hp = q ? hold1 : hold0;
            const float hnew = (1.f - zz) * nn + zz * hp;
            if (q) hold1 = hnew; else hold0 = hnew;
            const int row = r0 + lq * 4 + (kh * 2 + q);
            st_agent_u16(hw_ + row * NH + c_col, f2bf(hnew));  // sc1 -> IC
            if (t == NS - 1) hT[row * NH + c_col] = hnew;
        }

        // ---- phased 16-block barrier via relaxed agent atomics (no fences) ----
        if (t < NS - 1) {
            // __syncthreads drains vmcnt(0) per wave -> all sc1 h-stores ack'd
            __syncthreads();
            if (tid == 0) {
                __hip_atomic_fetch_add(cg + t, 1u, __ATOMIC_RELAXED, __HIP_MEMORY_SCOPE_AGENT);
                while (__hip_atomic_load(cg + t, __ATOMIC_RELAXED, __HIP_MEMORY_SCOPE_AGENT) < 16u) {}
            }
            __syncthreads();
        }
    }
}

// out[256,1000] = hT[256,512] @ W_head^T + b_head, pure fp32.
__global__ void __launch_bounds__(256, 1) gru_head(
    const float* __restrict__ hT,
    const float* __restrict__ Wh,
    const float* __restrict__ bh,
    float* __restrict__ out)
{
    __shared__ float hs[16 * 512];
    const int tid = threadIdx.x;
    const int rg  = blockIdx.x;   // 16 row groups of 16
    const int cgp = blockIdx.y;   // 16 col groups of 64
    const float* src = hT + rg * (16 * 512);
#pragma unroll
    for (int i = 0; i < 32; ++i) hs[tid + 256 * i] = src[tid + 256 * i];
    __syncthreads();
    const int col = (cgp << 6) + (tid & 63);
    const int rb  = (tid >> 6) << 2;
    if (col < NC) {
        const float* wr = Wh + col * NH;
        float a0 = 0.f, a1 = 0.f, a2 = 0.f, a3 = 0.f;
        for (int k = 0; k < NH; k += 4) {
            const f32x4 wv = *(const f32x4*)(wr + k);
            const f32x4 h0 = *(const f32x4*)&hs[(rb + 0) * NH + k];
            const f32x4 h1 = *(const f32x4*)&hs[(rb + 1) * NH + k];
            const f32x4 h2 = *(const f32x4*)&hs[(rb + 2) * NH + k];
            const f32x4 h3 = *(const f32x4*)&hs[(rb + 3) * NH + k];
#pragma unroll
            for (int j = 0; j < 4; ++j) {
                a0 = fmaf(wv[j], h0[j], a0);
                a1 = fmaf(wv[j], h1[j], a1);
                a2 = fmaf(wv[j], h2[j], a2);
                a3 = fmaf(wv[j], h3[j], a3);
            }
        }
        const float bb = bh[col];
        const int orow = (rg << 4) + rb;
        out[(orow + 0) * NC + col] = a0 + bb;
        out[(orow + 1) * NC + col] = a1 + bb;
        out[(orow + 2) * NC + col] = a2 + bb;
        out[(orow + 3) * NC + col] = a3 + bb;
    }
}

extern "C" void kernel_launch(void* const* d_in, const int* in_sizes, int n_in,
                              void* d_out, int out_size, void* d_ws, size_t ws_size,
                              hipStream_t stream)
{
    (void)in_sizes; (void)n_in; (void)out_size; (void)ws_size;
    const float* x     = (const float*)d_in[0];
    const float* Wih   = (const float*)d_in[1];
    const float* Whh   = (const float*)d_in[2];
    const float* bih   = (const float*)d_in[3];
    const float* bhh   = (const float*)d_in[4];
    const float* Whead = (const float*)d_in[5];
    const float* bhead = (const float*)d_in[6];
    float* out = (float*)d_out;

    char* ws = (char*)d_ws;
    unsigned short* hbuf = (unsigned short*)ws;                        // 2*256*512 bf16 = 512KB
    unsigned int*   cnt  = (unsigned int*)(ws + 2 * NB * NH * 2);      // 16*512 u32  = 32KB
    float*          hT   = (float*)(ws + 2 * NB * NH * 2 + 16 * NS * 4); // 256*512 f32 = 512KB

    gru_init_ws<<<144, 256, 0, stream>>>((unsigned long long*)hbuf, (unsigned long long*)cnt);
    gru_scan<<<256, 256, 0, stream>>>(x, Wih, Whh, bih, bhh, hbuf, hT, cnt);
    gru_head<<<dim3(16, 16), 256, 0, stream>>>(hT, Whead, bhead, out);
}